// Round 6
// baseline (309.081 us; speedup 1.0000x reference)
//
#include <hip/hip_runtime.h>
#include <cstddef>

#define TB   2
#define TT   2048
#define TC   768
#define NHD  12
#define HDD  64
#define QKVN 2304
#define BTM  4096   // TB*TT

// ws layout (float offsets)
#define FF_OFF   9437184ull    // qkv = BTM*QKVN floats
#define YTB_OFF  17825792ull   // + TB*TT*TT; ytb bf16 (BTM*TC uint16 = 1572864 floats)
#define GSUM_OFF 19398656ull   // + 1572864; gsum TB*32*TT floats
#define FSUM_OFF 19529728ull   // + 131072;  fsum TB*TT floats
#define YSZ      3145728       // BTM*TC

typedef __attribute__((ext_vector_type(8))) short bf16x8;
typedef __attribute__((ext_vector_type(4))) float f32x4;

__device__ inline unsigned short f2bf(float f) {
    unsigned u = __float_as_uint(f);
    return (unsigned short)((u + 0x7fffu + ((u >> 16) & 1u)) >> 16);
}

// ------------------------------------------------------- fp32 -> bf16 cast
__global__ __launch_bounds__(256) void castbf(
    const float* __restrict__ in, unsigned short* __restrict__ out, int n8)
{
    int idx = blockIdx.x * 256 + threadIdx.x;
    if (idx >= n8) return;
    const float4* p = (const float4*)(in + (size_t)idx * 8);
    float4 a = p[0], b = p[1];
    union { unsigned short us[8]; uint4 u4; } r;
    r.us[0] = f2bf(a.x); r.us[1] = f2bf(a.y); r.us[2] = f2bf(a.z); r.us[3] = f2bf(a.w);
    r.us[4] = f2bf(b.x); r.us[5] = f2bf(b.y); r.us[6] = f2bf(b.z); r.us[7] = f2bf(b.w);
    *(uint4*)(out + (size_t)idx * 8) = r.u4;
}

// ------------------------------------- W[K][N] fp32 -> Wt[N][K] bf16 (64x64)
__global__ __launch_bounds__(256) void tcast(
    const float* __restrict__ W, unsigned short* __restrict__ Wt, int K, int N)
{
    __shared__ unsigned short T[64][80];
    const int tid = threadIdx.x;
    const int k0 = blockIdx.x * 64, n0 = blockIdx.y * 64;
#pragma unroll
    for (int u = 0; u < 4; ++u) {
        int f = u * 256 + tid;
        int kr = f >> 4, nc = (f & 15) * 4;
        float4 v = *(const float4*)(W + (size_t)(k0 + kr) * N + n0 + nc);
        T[nc + 0][kr] = f2bf(v.x); T[nc + 1][kr] = f2bf(v.y);
        T[nc + 2][kr] = f2bf(v.z); T[nc + 3][kr] = f2bf(v.w);
    }
    __syncthreads();
#pragma unroll
    for (int u = 0; u < 2; ++u) {
        int f = u * 256 + tid;
        int nr = f >> 3, kc = (f & 7) * 8;
        *(uint4*)(Wt + (size_t)(n0 + nr) * K + k0 + kc) = *(uint4*)&T[nr][kc];
    }
}

// --------------------------------------------------------- bf16 MFMA GEMM
__global__ __launch_bounds__(256) void gemm_bf16(
    const unsigned short* __restrict__ A, const unsigned short* __restrict__ Bt,
    const float* __restrict__ bias, float* __restrict__ C,
    int M, int N, int K)
{
    __shared__ unsigned short As[128 * 64];
    __shared__ unsigned short Bs[128 * 64];
    const int tid = threadIdx.x;
    const int w = tid >> 6, lane = tid & 63;
    const int row0 = blockIdx.y * 128, col0 = blockIdx.x * 128;
    const int moff = (w >> 1) * 64, noff = (w & 1) * 64;
    const int lm = lane & 15, quad = lane >> 4;

    f32x4 acc[4][4];
#pragma unroll
    for (int i = 0; i < 4; ++i)
#pragma unroll
        for (int j = 0; j < 4; ++j) acc[i][j] = (f32x4){0.f, 0.f, 0.f, 0.f};

    for (int k0 = 0; k0 < K; k0 += 64) {
        __syncthreads();
#pragma unroll
        for (int u = 0; u < 4; ++u) {
            int unit = u * 256 + tid;
            int r = unit >> 3, kq = unit & 7;
            int kqs = kq ^ (r & 7);
            bf16x8 va = *(const bf16x8*)(A + (size_t)(row0 + r) * K + k0 + kq * 8);
            *(bf16x8*)&As[r * 64 + kqs * 8] = va;
            bf16x8 vb = *(const bf16x8*)(Bt + (size_t)(col0 + r) * K + k0 + kq * 8);
            *(bf16x8*)&Bs[r * 64 + kqs * 8] = vb;
        }
        __syncthreads();
#pragma unroll
        for (int kh = 0; kh < 2; ++kh) {
            const int kqb = kh * 4 + quad;
            bf16x8 af[4], bfr[4];
#pragma unroll
            for (int i = 0; i < 4; ++i) {
                int mr = moff + i * 16 + lm;
                af[i] = *(const bf16x8*)&As[mr * 64 + (kqb ^ (mr & 7)) * 8];
                int nr = noff + i * 16 + lm;
                bfr[i] = *(const bf16x8*)&Bs[nr * 64 + (kqb ^ (nr & 7)) * 8];
            }
#pragma unroll
            for (int i = 0; i < 4; ++i)
#pragma unroll
                for (int j = 0; j < 4; ++j)
                    acc[i][j] = __builtin_amdgcn_mfma_f32_16x16x32_bf16(
                        af[i], bfr[j], acc[i][j], 0, 0, 0);
        }
    }

#pragma unroll
    for (int j = 0; j < 4; ++j) {
        int n = col0 + noff + j * 16 + lm;
        float bv = bias[n];
#pragma unroll
        for (int i = 0; i < 4; ++i) {
            int mbase = row0 + moff + i * 16 + quad * 4;
#pragma unroll
            for (int r = 0; r < 4; ++r)
                C[(size_t)(mbase + r) * N + n] = acc[i][j][r] + bv;
        }
    }
}

// ------------------------------------------- head-0 S + fused column sums
// S[b,t,s] = (0<s && s<t) ? relu(q0.k0/8) : 0; also gsum[b][t0/64][s] =
// column sum of the 64-row group (feeds the 32-group scan; pass1 deleted).
__global__ __launch_bounds__(256) void s_head0_kernel(
    const float* __restrict__ qkv, float* __restrict__ S, float* __restrict__ gsum)
{
    const int s0 = blockIdx.x * 64, t0 = blockIdx.y * 64, b = blockIdx.z;
    const int tid = threadIdx.x;
    const int w = tid >> 6, lane = tid & 63;
    const int lm = lane & 15, quad = lane >> 4;

    if (s0 > t0) {  // fully above diagonal
        float4 z = make_float4(0.f, 0.f, 0.f, 0.f);
#pragma unroll
        for (int i = 0; i < 4; ++i) {
            int f = i * 256 + tid;      // 0..1023 -> (row, col4)
            int r = f >> 4, c = (f & 15) * 4;
            *(float4*)(S + ((size_t)b * TT + t0 + r) * TT + s0 + c) = z;
        }
        if (tid < 64) gsum[((size_t)b * 32 + blockIdx.y) * TT + s0 + tid] = 0.f;
        return;
    }

    __shared__ unsigned short Ks[64 * 64];
    __shared__ float colpart[4][64];

    // stage K0 tile [s][d] bf16 swizzled
#pragma unroll
    for (int u = 0; u < 2; ++u) {
        int unit = u * 256 + tid;
        int r = unit >> 3, kq = unit & 7;
        const float* kp = qkv + ((size_t)(b * TT) + s0 + r) * QKVN + 768 + kq * 8;
        float4 a = *(const float4*)kp;
        float4 c = *(const float4*)(kp + 4);
        union { unsigned short us[8]; bf16x8 v; } uu;
        uu.us[0] = f2bf(a.x); uu.us[1] = f2bf(a.y); uu.us[2] = f2bf(a.z); uu.us[3] = f2bf(a.w);
        uu.us[4] = f2bf(c.x); uu.us[5] = f2bf(c.y); uu.us[6] = f2bf(c.z); uu.us[7] = f2bf(c.w);
        *(bf16x8*)&Ks[r * 64 + (kq ^ (r & 7)) * 8] = uu.v;
    }
    // Q0 A-frags: rows t0 + w*16 + lm
    bf16x8 af[2];
#pragma unroll
    for (int kh = 0; kh < 2; ++kh) {
        const float* qp = qkv + ((size_t)(b * TT) + t0 + w * 16 + lm) * QKVN + kh * 32 + quad * 8;
        float4 a = *(const float4*)qp;
        float4 c = *(const float4*)(qp + 4);
        union { unsigned short us[8]; bf16x8 v; } uu;
        uu.us[0] = f2bf(a.x); uu.us[1] = f2bf(a.y); uu.us[2] = f2bf(a.z); uu.us[3] = f2bf(a.w);
        uu.us[4] = f2bf(c.x); uu.us[5] = f2bf(c.y); uu.us[6] = f2bf(c.z); uu.us[7] = f2bf(c.w);
        af[kh] = uu.v;
    }
    __syncthreads();

    f32x4 acc[4];
#pragma unroll
    for (int nj = 0; nj < 4; ++nj) acc[nj] = (f32x4){0.f, 0.f, 0.f, 0.f};
#pragma unroll
    for (int kh = 0; kh < 2; ++kh)
#pragma unroll
        for (int nj = 0; nj < 4; ++nj) {
            int sr = nj * 16 + lm;
            bf16x8 kb = *(const bf16x8*)&Ks[sr * 64 + ((kh * 4 + quad) ^ (sr & 7)) * 8];
            acc[nj] = __builtin_amdgcn_mfma_f32_16x16x32_bf16(af[kh], kb, acc[nj], 0, 0, 0);
        }

    // mask + relu + store + column partial
#pragma unroll
    for (int nj = 0; nj < 4; ++nj) {
        int s = s0 + nj * 16 + lm;
        float cs = 0.f;
#pragma unroll
        for (int r = 0; r < 4; ++r) {
            int t = t0 + w * 16 + quad * 4 + r;
            float v = (s > 0 && s < t) ? fmaxf(acc[nj][r] * 0.125f, 0.f) : 0.f;
            S[((size_t)b * TT + t) * TT + s] = v;
            cs += v;
        }
        cs += __shfl_xor(cs, 16, 64);
        cs += __shfl_xor(cs, 32, 64);
        if (quad == 0) colpart[w][nj * 16 + lm] = cs;
    }
    __syncthreads();
    if (tid < 64) {
        float g = colpart[0][tid] + colpart[1][tid] + colpart[2][tid] + colpart[3][tid];
        gsum[((size_t)b * 32 + blockIdx.y) * TT + s0 + tid] = g;
    }
}

// -------------------- scan of 32 group sums (exclusive) + zero fsum
__global__ void scan_pass2(float* __restrict__ gsum, float* __restrict__ fsum)
{
    int idx = blockIdx.x * 256 + threadIdx.x;  // 0..4095
    int b = idx >> 11, s = idx & 2047;
    fsum[idx] = 0.f;
    float acc = 0.f;
#pragma unroll
    for (int g = 0; g < 32; ++g) {
        size_t a = ((size_t)b * 32 + g) * TT + s;
        float v = gsum[a];
        gsum[a] = acc;
        acc += v;
    }
}

// ------ in-place S->FF within 64-row groups + fused row-sum of clip (ffsum)
__global__ void scan_pass3(float* __restrict__ S, const float* __restrict__ gsum,
                           float* __restrict__ fsum)
{
    int s = blockIdx.x * 256 + threadIdx.x;
    int g = blockIdx.y, b = blockIdx.z;
    int lane = threadIdx.x & 63;
    float acc = gsum[((size_t)b * 32 + g) * TT + s];
    float* base = S + ((size_t)b * TT + g * 64) * TT + s;
#pragma unroll 2
    for (int r = 0; r < 64; ++r) {
        float v = base[(size_t)r * TT];
        base[(size_t)r * TT] = acc;
        float c = fminf(fmaxf(acc, 0.f), 1.f);
        c += __shfl_xor(c, 1, 64);
        c += __shfl_xor(c, 2, 64);
        c += __shfl_xor(c, 4, 64);
        c += __shfl_xor(c, 8, 64);
        c += __shfl_xor(c, 16, 64);
        c += __shfl_xor(c, 32, 64);
        if (lane == 0) atomicAdd(&fsum[(size_t)b * TT + g * 64 + r], c);
        acc += v;
    }
}

// ----------------------------------------------------- M[0,b,i,j] = i - FS[b,j]
__global__ void mout_kernel(const float* __restrict__ FS, float* __restrict__ Mo)
{
    size_t idx = (size_t)blockIdx.x * 256 + threadIdx.x;
    int j = (int)(idx & 2047);
    int i = (int)((idx >> 11) & 2047);
    int b = (int)(idx >> 22);
    Mo[idx] = (float)i - FS[b * TT + j];
}

// -------------------------------------------- flash attention, bf16 MFMA
// v5: 128 q-rows per block (2 q-subtiles per wave). S^T = mfma(K,Q) keeps Q
// in registers; P round-trips LDS; V transposed at stage. K/V staged-tile
// count halves vs 64-row blocks. Heavy-qb-first interleaved dispatch.
__global__ __launch_bounds__(256) void attn_kernel(
    const float* __restrict__ qkv, const float* __restrict__ FF,
    unsigned short* __restrict__ Yb)
{
    const int x = blockIdx.x;            // 0..383
    const int qb = 15 - x / 24;          // heavy first
    const int bh = x % 24;
    const int h = bh % NHD, b = bh / NHD;
    const int t0 = qb * 128;

    const int tid = threadIdx.x;
    const int w = tid >> 6, lane = tid & 63;
    const int lm = lane & 15, quad = lane >> 4;

    __shared__ unsigned short Ks[64 * 64];
    __shared__ unsigned short Vt[64 * 64];
    __shared__ unsigned short Ps[128 * 64];

    // Q fragments: qsub qs -> rows tq = t0 + w*32 + qs*16 + lm
    bf16x8 qf[2][2];
    int tq[2];
#pragma unroll
    for (int qs = 0; qs < 2; ++qs) {
        tq[qs] = t0 + w * 32 + qs * 16 + lm;
#pragma unroll
        for (int kh = 0; kh < 2; ++kh) {
            const float* qp = qkv + ((size_t)(b * TT) + tq[qs]) * QKVN + h * 64 + kh * 32 + quad * 8;
            float4 a = *(const float4*)qp;
            float4 c = *(const float4*)(qp + 4);
            union { unsigned short us[8]; bf16x8 v; } u;
            u.us[0] = f2bf(a.x); u.us[1] = f2bf(a.y); u.us[2] = f2bf(a.z); u.us[3] = f2bf(a.w);
            u.us[4] = f2bf(c.x); u.us[5] = f2bf(c.y); u.us[6] = f2bf(c.z); u.us[7] = f2bf(c.w);
            qf[qs][kh] = u.v;
        }
    }

    f32x4 accO[2][4];
#pragma unroll
    for (int m = 0; m < 2; ++m)
#pragma unroll
        for (int j = 0; j < 4; ++j) accO[m][j] = (f32x4){0.f, 0.f, 0.f, 0.f};
    float m_c[2] = {-3.0e38f, -3.0e38f}, l_c[2] = {0.f, 0.f};

    const int ntile = qb * 2 + 2;
#pragma unroll 1
    for (int it = 0; it < ntile; ++it) {
        const int s0 = it * 64;
        __syncthreads();

        // ---- stage K [s][d] swizzled ----
#pragma unroll
        for (int u = 0; u < 2; ++u) {
            int unit = u * 256 + tid;
            int r = unit >> 3, kq = unit & 7;
            const float* kp = qkv + ((size_t)(b * TT) + s0 + r) * QKVN + 768 + h * 64 + kq * 8;
            float4 a = *(const float4*)kp;
            float4 c = *(const float4*)(kp + 4);
            union { unsigned short us[8]; bf16x8 v; } uu;
            uu.us[0] = f2bf(a.x); uu.us[1] = f2bf(a.y); uu.us[2] = f2bf(a.z); uu.us[3] = f2bf(a.w);
            uu.us[4] = f2bf(c.x); uu.us[5] = f2bf(c.y); uu.us[6] = f2bf(c.z); uu.us[7] = f2bf(c.w);
            *(bf16x8*)&Ks[r * 64 + (kq ^ (r & 7)) * 8] = uu.v;
        }
        // ---- stage V^T [d][s] ----
        {
            int s = lane;
            const float* vp = qkv + ((size_t)(b * TT) + s0 + s) * QKVN + 1536 + h * 64 + w * 16;
            float4 v0 = *(const float4*)(vp + 0);
            float4 v1 = *(const float4*)(vp + 4);
            float4 v2 = *(const float4*)(vp + 8);
            float4 v3 = *(const float4*)(vp + 12);
            float vv[16] = {v0.x, v0.y, v0.z, v0.w, v1.x, v1.y, v1.z, v1.w,
                            v2.x, v2.y, v2.z, v2.w, v3.x, v3.y, v3.z, v3.w};
            const int sg = s >> 3, sl = s & 7;
#pragma unroll
            for (int dd = 0; dd < 16; ++dd) {
                int d = w * 16 + dd;
                Vt[d * 64 + (sg ^ (d & 7)) * 8 + sl] = f2bf(vv[dd]);
            }
        }
        __syncthreads();

        float alpha[2];
#pragma unroll
        for (int qs = 0; qs < 2; ++qs) {
            // S^T tile: D[m=s][n=q]
            f32x4 accS[4];
#pragma unroll
            for (int mi = 0; mi < 4; ++mi) accS[mi] = (f32x4){0.f, 0.f, 0.f, 0.f};
#pragma unroll
            for (int kh = 0; kh < 2; ++kh)
#pragma unroll
                for (int mi = 0; mi < 4; ++mi) {
                    int sr = mi * 16 + lm;
                    bf16x8 kf = *(const bf16x8*)&Ks[sr * 64 + ((kh * 4 + quad) ^ (sr & 7)) * 8];
                    accS[mi] = __builtin_amdgcn_mfma_f32_16x16x32_bf16(kf, qf[qs][kh], accS[mi], 0, 0, 0);
                }

            float sc[4][4];
            float rm = -3.0e38f;
            const float* ffrow = FF + ((size_t)(b * TT) + tq[qs]) * TT + s0;
            const bool diag = (it >= qb * 2);
#pragma unroll
            for (int mi = 0; mi < 4; ++mi) {
                float4 f4 = *(const float4*)(ffrow + mi * 16 + quad * 4);
                float fa[4] = {f4.x, f4.y, f4.z, f4.w};
#pragma unroll
                for (int r = 0; r < 4; ++r) {
                    float v = accS[mi][r] * 0.125f - fa[r];
                    if (diag && s0 + mi * 16 + quad * 4 + r > tq[qs]) v = -3.0e38f;
                    sc[mi][r] = v;
                    rm = fmaxf(rm, v);
                }
            }
            rm = fmaxf(rm, __shfl_xor(rm, 16, 64));
            rm = fmaxf(rm, __shfl_xor(rm, 32, 64));
            float mnew = fmaxf(m_c[qs], rm);
            alpha[qs] = __expf(m_c[qs] - mnew);
            m_c[qs] = mnew;
            float rs = 0.f;
#pragma unroll
            for (int mi = 0; mi < 4; ++mi)
#pragma unroll
                for (int r = 0; r < 4; ++r) {
                    float p = __expf(sc[mi][r] - mnew);
                    sc[mi][r] = p;
                    rs += p;
                }
            rs += __shfl_xor(rs, 16, 64);
            rs += __shfl_xor(rs, 32, 64);
            l_c[qs] = l_c[qs] * alpha[qs] + rs;

            // store P rows (wave-private region)
            const int qrow = w * 32 + qs * 16 + lm;
#pragma unroll
            for (int mi = 0; mi < 4; ++mi)
#pragma unroll
                for (int r = 0; r < 4; ++r) {
                    int sr = mi * 16 + quad * 4 + r;
                    Ps[qrow * 64 + ((sr >> 3) ^ (qrow & 7)) * 8 + (sr & 7)] = f2bf(sc[mi][r]);
                }
        }

        // rescale O
#pragma unroll
        for (int m = 0; m < 2; ++m) {
            float a_r[4];
#pragma unroll
            for (int r = 0; r < 4; ++r) a_r[r] = __shfl(alpha[m], quad * 4 + r, 64);
#pragma unroll
            for (int nj = 0; nj < 4; ++nj)
#pragma unroll
                for (int r = 0; r < 4; ++r) accO[m][nj][r] *= a_r[r];
        }

        // O += P V
        bf16x8 pf[2][2];
#pragma unroll
        for (int m = 0; m < 2; ++m)
#pragma unroll
            for (int kh = 0; kh < 2; ++kh) {
                int qrow = w * 32 + m * 16 + lm;
                pf[m][kh] = *(const bf16x8*)&Ps[qrow * 64 + ((kh * 4 + quad) ^ (qrow & 7)) * 8];
            }
#pragma unroll
        for (int kh = 0; kh < 2; ++kh)
#pragma unroll
            for (int nj = 0; nj < 4; ++nj) {
                int dr = nj * 16 + lm;
                bf16x8 vf = *(const bf16x8*)&Vt[dr * 64 + ((kh * 4 + quad) ^ (dr & 7)) * 8];
#pragma unroll
                for (int m = 0; m < 2; ++m)
                    accO[m][nj] = __builtin_amdgcn_mfma_f32_16x16x32_bf16(pf[m][kh], vf, accO[m][nj], 0, 0, 0);
            }
    }

    // epilogue
#pragma unroll
    for (int m = 0; m < 2; ++m) {
        float l_r[4];
#pragma unroll
        for (int r = 0; r < 4; ++r) l_r[r] = __shfl(l_c[m], quad * 4 + r, 64);
#pragma unroll
        for (int nj = 0; nj < 4; ++nj)
#pragma unroll
            for (int r = 0; r < 4; ++r) {
                int trow = t0 + w * 32 + m * 16 + quad * 4 + r;
                Yb[((size_t)(b * TT) + trow) * TC + h * 64 + nj * 16 + lm] =
                    f2bf(accO[m][nj][r] / l_r[r]);
            }
    }
}

// ---------------------------------------------------------------------- launch
extern "C" void kernel_launch(void* const* d_in, const int* in_sizes, int n_in,
                              void* d_out, int out_size, void* d_ws, size_t ws_size,
                              hipStream_t stream)
{
    const float* x      = (const float*)d_in[0];
    const float* W_attn = (const float*)d_in[1];
    const float* b_attn = (const float*)d_in[2];
    const float* W_proj = (const float*)d_in[3];
    const float* b_proj = (const float*)d_in[4];
    float* out = (float*)d_out;
    float* ws  = (float*)d_ws;

    float* qkv  = ws;                 // [4096, 2304] fp32
    float* FFb  = ws + FF_OFF;        // [B, T, T]   S -> FF in place
    float* gsum = ws + GSUM_OFF;      // [B, 32, T]
    float* fsum = ws + FSUM_OFF;      // [B, T]

    unsigned short* xb  = (unsigned short*)(ws + FF_OFF);   // pre-S alias
    unsigned short* WtA = xb + (size_t)BTM * TC;
    unsigned short* WtP = (unsigned short*)(ws + FF_OFF);   // post-attn alias
    unsigned short* ytb = (unsigned short*)(ws + YTB_OFF);

    castbf<<<dim3(1536), dim3(256), 0, stream>>>(x, xb, BTM * TC / 8);
    tcast<<<dim3(TC / 64, QKVN / 64), dim3(256), 0, stream>>>(W_attn, WtA, TC, QKVN);

    gemm_bf16<<<dim3(QKVN / 128, BTM / 128), dim3(256), 0, stream>>>(
        xb, WtA, b_attn, qkv, BTM, QKVN, TC);

    s_head0_kernel<<<dim3(TT / 64, TT / 64, TB), dim3(256), 0, stream>>>(qkv, FFb, gsum);

    scan_pass2<<<dim3(TB * TT / 256), dim3(256), 0, stream>>>(gsum, fsum);
    scan_pass3<<<dim3(TT / 256, 32, TB), dim3(256), 0, stream>>>(FFb, gsum, fsum);

    attn_kernel<<<dim3(16 * NHD * TB), dim3(256), 0, stream>>>(qkv, FFb, ytb);

    tcast<<<dim3(TC / 64, TC / 64), dim3(256), 0, stream>>>(W_proj, WtP, TC, TC);

    gemm_bf16<<<dim3(TC / 128, BTM / 128), dim3(256), 0, stream>>>(
        ytb, WtP, b_proj, out, BTM, TC, TC);

    mout_kernel<<<dim3((unsigned)((size_t)TB * TT * TT / 256)), dim3(256), 0, stream>>>(
        fsum, out + YSZ);
}

// Round 7
// 258.206 us; speedup vs baseline: 1.1970x; 1.1970x over previous
//
#include <hip/hip_runtime.h>
#include <cstddef>

#define TB   2
#define TT   2048
#define TC   768
#define NHD  12
#define HDD  64
#define QKVN 2304
#define BTM  4096   // TB*TT

// ws layout (float offsets)
#define FF_OFF   9437184ull    // qkvb region (bf16 [4096][2304] uses half)
#define YTB_OFF  17825792ull   // + TB*TT*TT; ytb bf16
#define GSUM_OFF 19398656ull   // gsum TB*32*TT floats
#define FSUM_OFF 19529728ull   // fsum TB*TT floats
#define YSZ      3145728       // BTM*TC

typedef __attribute__((ext_vector_type(8))) short bf16x8;
typedef __attribute__((ext_vector_type(4))) float f32x4;

__device__ inline unsigned short f2bf(float f) {
    unsigned u = __float_as_uint(f);
    return (unsigned short)((u + 0x7fffu + ((u >> 16) & 1u)) >> 16);
}

// ------------------------------------------------------- fp32 -> bf16 cast
__global__ __launch_bounds__(256) void castbf(
    const float* __restrict__ in, unsigned short* __restrict__ out, int n8)
{
    int idx = blockIdx.x * 256 + threadIdx.x;
    if (idx >= n8) return;
    const float4* p = (const float4*)(in + (size_t)idx * 8);
    float4 a = p[0], b = p[1];
    union { unsigned short us[8]; uint4 u4; } r;
    r.us[0] = f2bf(a.x); r.us[1] = f2bf(a.y); r.us[2] = f2bf(a.z); r.us[3] = f2bf(a.w);
    r.us[4] = f2bf(b.x); r.us[5] = f2bf(b.y); r.us[6] = f2bf(b.z); r.us[7] = f2bf(b.w);
    *(uint4*)(out + (size_t)idx * 8) = r.u4;
}

// ------------------------------------- W[K][N] fp32 -> Wt[N][K] bf16 (64x64)
__global__ __launch_bounds__(256) void tcast(
    const float* __restrict__ W, unsigned short* __restrict__ Wt, int K, int N)
{
    __shared__ unsigned short T[64][80];
    const int tid = threadIdx.x;
    const int k0 = blockIdx.x * 64, n0 = blockIdx.y * 64;
#pragma unroll
    for (int u = 0; u < 4; ++u) {
        int f = u * 256 + tid;
        int kr = f >> 4, nc = (f & 15) * 4;
        float4 v = *(const float4*)(W + (size_t)(k0 + kr) * N + n0 + nc);
        T[nc + 0][kr] = f2bf(v.x); T[nc + 1][kr] = f2bf(v.y);
        T[nc + 2][kr] = f2bf(v.z); T[nc + 3][kr] = f2bf(v.w);
    }
    __syncthreads();
#pragma unroll
    for (int u = 0; u < 2; ++u) {
        int f = u * 256 + tid;
        int nr = f >> 3, kc = (f & 7) * 8;
        *(uint4*)(Wt + (size_t)(n0 + nr) * K + k0 + kc) = *(uint4*)&T[nr][kc];
    }
}

// --------------------------------------------------------- bf16 MFMA GEMM
// C = A @ Bt^T + bias. BF16OUT selects bf16 vs fp32 output buffer.
template <bool BF16OUT>
__global__ __launch_bounds__(256) void gemm_bf16(
    const unsigned short* __restrict__ A, const unsigned short* __restrict__ Bt,
    const float* __restrict__ bias, float* __restrict__ C,
    unsigned short* __restrict__ Cb, int M, int N, int K)
{
    __shared__ unsigned short As[128 * 64];
    __shared__ unsigned short Bs[128 * 64];
    const int tid = threadIdx.x;
    const int w = tid >> 6, lane = tid & 63;
    const int row0 = blockIdx.y * 128, col0 = blockIdx.x * 128;
    const int moff = (w >> 1) * 64, noff = (w & 1) * 64;
    const int lm = lane & 15, quad = lane >> 4;

    f32x4 acc[4][4];
#pragma unroll
    for (int i = 0; i < 4; ++i)
#pragma unroll
        for (int j = 0; j < 4; ++j) acc[i][j] = (f32x4){0.f, 0.f, 0.f, 0.f};

    for (int k0 = 0; k0 < K; k0 += 64) {
        __syncthreads();
#pragma unroll
        for (int u = 0; u < 4; ++u) {
            int unit = u * 256 + tid;
            int r = unit >> 3, kq = unit & 7;
            int kqs = kq ^ (r & 7);
            bf16x8 va = *(const bf16x8*)(A + (size_t)(row0 + r) * K + k0 + kq * 8);
            *(bf16x8*)&As[r * 64 + kqs * 8] = va;
            bf16x8 vb = *(const bf16x8*)(Bt + (size_t)(col0 + r) * K + k0 + kq * 8);
            *(bf16x8*)&Bs[r * 64 + kqs * 8] = vb;
        }
        __syncthreads();
#pragma unroll
        for (int kh = 0; kh < 2; ++kh) {
            const int kqb = kh * 4 + quad;
            bf16x8 af[4], bfr[4];
#pragma unroll
            for (int i = 0; i < 4; ++i) {
                int mr = moff + i * 16 + lm;
                af[i] = *(const bf16x8*)&As[mr * 64 + (kqb ^ (mr & 7)) * 8];
                int nr = noff + i * 16 + lm;
                bfr[i] = *(const bf16x8*)&Bs[nr * 64 + (kqb ^ (nr & 7)) * 8];
            }
#pragma unroll
            for (int i = 0; i < 4; ++i)
#pragma unroll
                for (int j = 0; j < 4; ++j)
                    acc[i][j] = __builtin_amdgcn_mfma_f32_16x16x32_bf16(
                        af[i], bfr[j], acc[i][j], 0, 0, 0);
        }
    }

#pragma unroll
    for (int j = 0; j < 4; ++j) {
        int n = col0 + noff + j * 16 + lm;
        float bv = bias[n];
#pragma unroll
        for (int i = 0; i < 4; ++i) {
            int mbase = row0 + moff + i * 16 + quad * 4;
#pragma unroll
            for (int r = 0; r < 4; ++r) {
                float v = acc[i][j][r] + bv;
                if (BF16OUT)
                    Cb[(size_t)(mbase + r) * N + n] = f2bf(v);
                else
                    C[(size_t)(mbase + r) * N + n] = v;
            }
        }
    }
}

// ------------------------------------------- head-0 S + fused column sums
// qkvb is bf16. S[b,t,s] = (0<s && s<t) ? relu(q0.k0/8) : 0; gsum gets the
// 64-row-group column sums (pass1 stays deleted).
__global__ __launch_bounds__(256) void s_head0_kernel(
    const unsigned short* __restrict__ qkvb, float* __restrict__ S,
    float* __restrict__ gsum)
{
    const int s0 = blockIdx.x * 64, t0 = blockIdx.y * 64, b = blockIdx.z;
    const int tid = threadIdx.x;
    const int w = tid >> 6, lane = tid & 63;
    const int lm = lane & 15, quad = lane >> 4;

    if (s0 > t0) {  // fully above diagonal
        float4 z = make_float4(0.f, 0.f, 0.f, 0.f);
#pragma unroll
        for (int i = 0; i < 4; ++i) {
            int f = i * 256 + tid;
            int r = f >> 4, c = (f & 15) * 4;
            *(float4*)(S + ((size_t)b * TT + t0 + r) * TT + s0 + c) = z;
        }
        if (tid < 64) gsum[((size_t)b * 32 + blockIdx.y) * TT + s0 + tid] = 0.f;
        return;
    }

    __shared__ unsigned short Ks[64 * 64];
    __shared__ float colpart[4][64];

    // stage K0 tile [s][d] swizzled (pure b128 copy)
#pragma unroll
    for (int u = 0; u < 2; ++u) {
        int unit = u * 256 + tid;
        int r = unit >> 3, kq = unit & 7;
        bf16x8 kv = *(const bf16x8*)(qkvb + ((size_t)(b * TT) + s0 + r) * QKVN + 768 + kq * 8);
        *(bf16x8*)&Ks[r * 64 + (kq ^ (r & 7)) * 8] = kv;
    }
    // Q0 A-frags: rows t0 + w*16 + lm
    bf16x8 af[2];
#pragma unroll
    for (int kh = 0; kh < 2; ++kh)
        af[kh] = *(const bf16x8*)(qkvb + ((size_t)(b * TT) + t0 + w * 16 + lm) * QKVN + kh * 32 + quad * 8);
    __syncthreads();

    f32x4 acc[4];
#pragma unroll
    for (int nj = 0; nj < 4; ++nj) acc[nj] = (f32x4){0.f, 0.f, 0.f, 0.f};
#pragma unroll
    for (int kh = 0; kh < 2; ++kh)
#pragma unroll
        for (int nj = 0; nj < 4; ++nj) {
            int sr = nj * 16 + lm;
            bf16x8 kb = *(const bf16x8*)&Ks[sr * 64 + ((kh * 4 + quad) ^ (sr & 7)) * 8];
            acc[nj] = __builtin_amdgcn_mfma_f32_16x16x32_bf16(af[kh], kb, acc[nj], 0, 0, 0);
        }

#pragma unroll
    for (int nj = 0; nj < 4; ++nj) {
        int s = s0 + nj * 16 + lm;
        float cs = 0.f;
#pragma unroll
        for (int r = 0; r < 4; ++r) {
            int t = t0 + w * 16 + quad * 4 + r;
            float v = (s > 0 && s < t) ? fmaxf(acc[nj][r] * 0.125f, 0.f) : 0.f;
            S[((size_t)b * TT + t) * TT + s] = v;
            cs += v;
        }
        cs += __shfl_xor(cs, 16, 64);
        cs += __shfl_xor(cs, 32, 64);
        if (quad == 0) colpart[w][nj * 16 + lm] = cs;
    }
    __syncthreads();
    if (tid < 64) {
        float g = colpart[0][tid] + colpart[1][tid] + colpart[2][tid] + colpart[3][tid];
        gsum[((size_t)b * 32 + blockIdx.y) * TT + s0 + tid] = g;
    }
}

// -------------------- exclusive scan of the 32 group sums
__global__ void scan_pass2(float* __restrict__ gsum)
{
    int idx = blockIdx.x * 256 + threadIdx.x;  // 0..4095
    int b = idx >> 11, s = idx & 2047;
    float acc = 0.f;
#pragma unroll
    for (int g = 0; g < 32; ++g) {
        size_t a = ((size_t)b * 32 + g) * TT + s;
        float v = gsum[a];
        gsum[a] = acc;
        acc += v;
    }
}

// -------------------- in-place S->FF within 64-row groups (simple)
__global__ void scan_pass3(float* __restrict__ S, const float* __restrict__ gsum)
{
    int s = blockIdx.x * 256 + threadIdx.x;
    int g = blockIdx.y, b = blockIdx.z;
    float acc = gsum[((size_t)b * 32 + g) * TT + s];
    float* base = S + ((size_t)b * TT + g * 64) * TT + s;
#pragma unroll 4
    for (int r = 0; r < 64; ++r) {
        float v = base[(size_t)r * TT];
        base[(size_t)r * TT] = acc;
        acc += v;
    }
}

// ------------------------------------------------- FF_sum[b,t] = sum clip(FF)
__global__ void ffsum_kernel(const float* __restrict__ FF, float* __restrict__ FS)
{
    int row = blockIdx.x;  // b*TT + t
    int tid = threadIdx.x;
    const float* p = FF + (size_t)row * TT;
    float acc = 0.f;
#pragma unroll
    for (int s = tid; s < TT; s += 256) {
        float v = p[s];
        acc += fminf(fmaxf(v, 0.f), 1.f);
    }
#pragma unroll
    for (int off = 32; off > 0; off >>= 1) acc += __shfl_down(acc, off, 64);
    __shared__ float red[4];
    if ((tid & 63) == 0) red[tid >> 6] = acc;
    __syncthreads();
    if (tid == 0) FS[row] = (red[0] + red[1]) + (red[2] + red[3]);
}

// ----------------------------------------------------- M[0,b,i,j] = i - FS[b,j]
__global__ void mout_kernel(const float* __restrict__ FS, float* __restrict__ Mo)
{
    size_t idx = (size_t)blockIdx.x * 256 + threadIdx.x;
    int j = (int)(idx & 2047);
    int i = (int)((idx >> 11) & 2047);
    int b = (int)(idx >> 22);
    Mo[idx] = (float)i - FS[b * TT + j];
}

// -------------------------------------------- flash attention, bf16 MFMA
// v6: the R5 64-q-row/768-block shape (measured best occupancy), staging
// from pre-cast bf16 qkv: K staging is a pure b128 copy, no cvt VALU.
__global__ __launch_bounds__(256) void attn_kernel(
    const unsigned short* __restrict__ qkvb, const float* __restrict__ FF,
    unsigned short* __restrict__ Yb)
{
    const int sblk = blockIdx.x;           // 0..767
    const int hi = sblk >> 5;              // 0..23
    const int tt = (sblk ^ hi) & 31;       // bijective fold per 32-group
    const int h = hi % NHD;
    const int b = hi / NHD;

    const int tid = threadIdx.x;
    const int w = tid >> 6, lane = tid & 63;
    const int lm = lane & 15, quad = lane >> 4;
    const int t0 = tt * 64;

    __shared__ unsigned short Ks[64 * 64];
    __shared__ unsigned short Vt[64 * 64];
    __shared__ unsigned short Ps[64 * 64];

    // Q B-fragments (n = q = w*16+lm, k = kh*32+quad*8+j)
    const int tq = t0 + w * 16 + lm;
    bf16x8 qf[2];
#pragma unroll
    for (int kh = 0; kh < 2; ++kh)
        qf[kh] = *(const bf16x8*)(qkvb + ((size_t)(b * TT) + tq) * QKVN + h * 64 + kh * 32 + quad * 8);

    f32x4 accO[4];
#pragma unroll
    for (int j = 0; j < 4; ++j) accO[j] = (f32x4){0.f, 0.f, 0.f, 0.f};
    float m_c = -3.0e38f, l_c = 0.f;

#pragma unroll 1
    for (int it = 0; it <= tt; ++it) {
        const int s0 = it * 64;
        __syncthreads();

        // ---- stage K [s][d] swizzled (b128 copy) ----
#pragma unroll
        for (int u = 0; u < 2; ++u) {
            int unit = u * 256 + tid;
            int r = unit >> 3, kq = unit & 7;
            bf16x8 kv = *(const bf16x8*)(qkvb + ((size_t)(b * TT) + s0 + r) * QKVN + 768 + h * 64 + kq * 8);
            *(bf16x8*)&Ks[r * 64 + (kq ^ (r & 7)) * 8] = kv;
        }
        // ---- stage V^T [d][s] ----
        {
            int s = lane;
            const unsigned short* vp = qkvb + ((size_t)(b * TT) + s0 + s) * QKVN + 1536 + h * 64 + w * 16;
            union { uint4 u4; unsigned short us[8]; } a, c;
            a.u4 = *(const uint4*)vp;
            c.u4 = *(const uint4*)(vp + 8);
            const int sg = s >> 3, sl = s & 7;
#pragma unroll
            for (int dd = 0; dd < 8; ++dd) {
                int d = w * 16 + dd;
                Vt[d * 64 + (sg ^ (d & 7)) * 8 + sl] = a.us[dd];
            }
#pragma unroll
            for (int dd = 8; dd < 16; ++dd) {
                int d = w * 16 + dd;
                Vt[d * 64 + (sg ^ (d & 7)) * 8 + sl] = c.us[dd - 8];
            }
        }
        __syncthreads();

        // ---- S^T = K Q^T: D[m=s][n=q] ----
        f32x4 accS[4];
#pragma unroll
        for (int mi = 0; mi < 4; ++mi) accS[mi] = (f32x4){0.f, 0.f, 0.f, 0.f};
#pragma unroll
        for (int kh = 0; kh < 2; ++kh)
#pragma unroll
            for (int mi = 0; mi < 4; ++mi) {
                int sr = mi * 16 + lm;
                bf16x8 kf = *(const bf16x8*)&Ks[sr * 64 + ((kh * 4 + quad) ^ (sr & 7)) * 8];
                accS[mi] = __builtin_amdgcn_mfma_f32_16x16x32_bf16(kf, qf[kh], accS[mi], 0, 0, 0);
            }

        // ---- logits + online softmax ----
        float sc[4][4];
        float rm = -3.0e38f;
        const float* ffrow = FF + ((size_t)(b * TT) + tq) * TT + s0;
#pragma unroll
        for (int mi = 0; mi < 4; ++mi) {
            float4 f4 = *(const float4*)(ffrow + mi * 16 + quad * 4);
            float fa[4] = {f4.x, f4.y, f4.z, f4.w};
#pragma unroll
            for (int r = 0; r < 4; ++r) {
                float v = accS[mi][r] * 0.125f - fa[r];
                if (it == tt && s0 + mi * 16 + quad * 4 + r > tq) v = -3.0e38f;
                sc[mi][r] = v;
                rm = fmaxf(rm, v);
            }
        }
        rm = fmaxf(rm, __shfl_xor(rm, 16, 64));
        rm = fmaxf(rm, __shfl_xor(rm, 32, 64));
        float mnew = fmaxf(m_c, rm);
        float alpha = __expf(m_c - mnew);
        m_c = mnew;
        float rs = 0.f;
#pragma unroll
        for (int mi = 0; mi < 4; ++mi)
#pragma unroll
            for (int r = 0; r < 4; ++r) {
                float p = __expf(sc[mi][r] - mnew);
                sc[mi][r] = p;
                rs += p;
            }
        rs += __shfl_xor(rs, 16, 64);
        rs += __shfl_xor(rs, 32, 64);
        l_c = l_c * alpha + rs;

        // ---- rescale O ----
        float a_r[4];
#pragma unroll
        for (int r = 0; r < 4; ++r) a_r[r] = __shfl(alpha, quad * 4 + r, 64);
#pragma unroll
        for (int nj = 0; nj < 4; ++nj)
#pragma unroll
            for (int r = 0; r < 4; ++r) accO[nj][r] *= a_r[r];

        // ---- store P[q][s] (wave-private rows) ----
        const int qrow = w * 16 + lm;
#pragma unroll
        for (int mi = 0; mi < 4; ++mi)
#pragma unroll
            for (int r = 0; r < 4; ++r) {
                int sr = mi * 16 + quad * 4 + r;
                Ps[qrow * 64 + ((sr >> 3) ^ (qrow & 7)) * 8 + (sr & 7)] = f2bf(sc[mi][r]);
            }

        // ---- O += P V ----
        bf16x8 pf[2];
#pragma unroll
        for (int kh = 0; kh < 2; ++kh)
            pf[kh] = *(const bf16x8*)&Ps[qrow * 64 + ((kh * 4 + quad) ^ (qrow & 7)) * 8];
#pragma unroll
        for (int kh = 0; kh < 2; ++kh)
#pragma unroll
            for (int nj = 0; nj < 4; ++nj) {
                int dr = nj * 16 + lm;
                bf16x8 vf = *(const bf16x8*)&Vt[dr * 64 + ((kh * 4 + quad) ^ (dr & 7)) * 8];
                accO[nj] = __builtin_amdgcn_mfma_f32_16x16x32_bf16(pf[kh], vf, accO[nj], 0, 0, 0);
            }
    }

    // ---- epilogue ----
    float l_r[4];
#pragma unroll
    for (int r = 0; r < 4; ++r) l_r[r] = __shfl(l_c, quad * 4 + r, 64);
#pragma unroll
    for (int nj = 0; nj < 4; ++nj)
#pragma unroll
        for (int r = 0; r < 4; ++r) {
            int trow = t0 + w * 16 + quad * 4 + r;
            Yb[((size_t)(b * TT) + trow) * TC + h * 64 + nj * 16 + lm] =
                f2bf(accO[nj][r] / l_r[r]);
        }
}

// ---------------------------------------------------------------------- launch
extern "C" void kernel_launch(void* const* d_in, const int* in_sizes, int n_in,
                              void* d_out, int out_size, void* d_ws, size_t ws_size,
                              hipStream_t stream)
{
    const float* x      = (const float*)d_in[0];
    const float* W_attn = (const float*)d_in[1];
    const float* b_attn = (const float*)d_in[2];
    const float* W_proj = (const float*)d_in[3];
    const float* b_proj = (const float*)d_in[4];
    float* out = (float*)d_out;
    float* ws  = (float*)d_ws;

    unsigned short* qkvb = (unsigned short*)ws;   // bf16 [4096][2304]
    float* FFb  = ws + FF_OFF;        // [B, T, T]   S -> FF in place
    float* gsum = ws + GSUM_OFF;      // [B, 32, T]
    float* fsum = ws + FSUM_OFF;      // [B, T]

    unsigned short* xb  = (unsigned short*)(ws + FF_OFF);   // pre-S alias
    unsigned short* WtA = xb + (size_t)BTM * TC;
    unsigned short* WtP = (unsigned short*)(ws + FF_OFF);   // post-attn alias
    unsigned short* ytb = (unsigned short*)(ws + YTB_OFF);

    castbf<<<dim3(1536), dim3(256), 0, stream>>>(x, xb, BTM * TC / 8);
    tcast<<<dim3(TC / 64, QKVN / 64), dim3(256), 0, stream>>>(W_attn, WtA, TC, QKVN);

    gemm_bf16<true><<<dim3(QKVN / 128, BTM / 128), dim3(256), 0, stream>>>(
        xb, WtA, b_attn, nullptr, qkvb, BTM, QKVN, TC);

    s_head0_kernel<<<dim3(TT / 64, TT / 64, TB), dim3(256), 0, stream>>>(qkvb, FFb, gsum);

    scan_pass2<<<dim3(TB * TT / 256), dim3(256), 0, stream>>>(gsum);
    scan_pass3<<<dim3(TT / 256, 32, TB), dim3(256), 0, stream>>>(FFb, gsum);

    ffsum_kernel<<<dim3(TB * TT), dim3(256), 0, stream>>>(FFb, fsum);

    attn_kernel<<<dim3(TT / 64 * NHD * TB), dim3(256), 0, stream>>>(qkvb, FFb, ytb);

    tcast<<<dim3(TC / 64, TC / 64), dim3(256), 0, stream>>>(W_proj, WtP, TC, TC);

    gemm_bf16<false><<<dim3(TC / 128, BTM / 128), dim3(256), 0, stream>>>(
        ytb, WtP, b_proj, out, nullptr, BTM, TC, TC);

    mout_kernel<<<dim3((unsigned)((size_t)TB * TT * TT / 256)), dim3(256), 0, stream>>>(
        fsum, out + YSZ);
}